// Round 5
// baseline (6325.837 us; speedup 1.0000x reference)
//
#include <hip/hip_runtime.h>
#include <hip/hip_bf16.h>

// bidirLSTM: T=8192 seq, V=1e6 vocab, E=60 emb, D=60 hidden, C=5 out.
// ALL tensor inputs are float32 (per reference setup_inputs); tokens int32.
// Output: float32[5].
//
// R5 structure: ONE WAVE per direction owns the whole recurrence.
//   Lane dd (0..59 active): holds h[dd], c[dd], and all 4 Whh rows of unit
//   dd as float2 pairs (240 VGPRs; launch_bounds(64,1) allows ~512).
//   Per step: ds_write_b32 h -> (same-wave lgkmcnt ordering, NO barrier)
//   -> 15 broadcast ds_read_b128 -> 120 v_pk_fma_f32 (float2 elementwise
//   fma) -> per-lane activations (no DPP reduce/gather at all).
//   gx prefetched as one dwordx4/step (gates_kernel permutes to
//   (dd, gate) float4 order), ring depth 4.
//   R4's 4-wave version spent ~300-400 cyc/step on the ds_write ->
//   barrier -> ds_read cross-wave round trip; this removes it.

#define T_LEN 8192
#define E_DIM 60
#define D_DIM 60
#define TB    32       // timesteps per block in gates kernel

typedef float v2f __attribute__((ext_vector_type(2)));

__device__ __forceinline__ float fast_rcp(float x) {
    return __builtin_amdgcn_rcpf(x);
}

// ---------------------------------------------------------------------------
// Kernel 1: gxp[(dir*T + t)*256 + p] with p = dd*4 + gate  (dd = p>>2,
// gate = p&3): unit dd's 4 gate pre-activations are one contiguous float4,
// exactly the scan kernel's per-lane dwordx4.
// ---------------------------------------------------------------------------
__global__ __launch_bounds__(256) void gates_kernel(
    const int*   __restrict__ tokens,
    const float* __restrict__ emb,
    const float* __restrict__ WxhL,
    const float* __restrict__ bxhL,
    const float* __restrict__ bhhL,
    const float* __restrict__ WxhR,
    const float* __restrict__ bxhR,
    const float* __restrict__ bhhR,
    float* __restrict__ gxp)
{
    const int dir = blockIdx.y;
    const float* Wxh = dir ? WxhR : WxhL;
    const float* bxh = dir ? bxhR : bxhL;
    const float* bhh = dir ? bhhR : bhhL;

    const int p = threadIdx.x;
    const int gate = p & 3;
    const int dd = p >> 2;          // 0..63
    const bool act = (dd < D_DIM);
    const int j = gate * 60 + (act ? dd : 0);

    float wx[E_DIM];
    float bj = 0.f;
    if (act) {
        const float4* row = (const float4*)(Wxh + (size_t)j * E_DIM); // 240 B stride
        #pragma unroll
        for (int i = 0; i < 15; ++i) {
            float4 v = row[i];
            wx[4 * i]     = v.x;
            wx[4 * i + 1] = v.y;
            wx[4 * i + 2] = v.z;
            wx[4 * i + 3] = v.w;
        }
        bj = bxh[j] + bhh[j];
    }

    __shared__ float xs[64];
    const int t0 = blockIdx.x * TB;
    for (int tt = 0; tt < TB; ++tt) {
        const int t = t0 + tt;
        const int idx = dir ? (T_LEN - 1 - t) : t;
        const int tok = tokens[idx];
        if (p < 15) {
            float4 v = ((const float4*)(emb + (size_t)tok * E_DIM))[p];
            xs[4 * p]     = v.x;
            xs[4 * p + 1] = v.y;
            xs[4 * p + 2] = v.z;
            xs[4 * p + 3] = v.w;
        }
        __syncthreads();
        float s = 0.f;
        if (act) {
            s = bj;
            #pragma unroll
            for (int k = 0; k < E_DIM; ++k) s += wx[k] * xs[k];
        }
        gxp[((size_t)dir * T_LEN + t) * 256 + p] = s;
        __syncthreads();
    }
}

// ---------------------------------------------------------------------------
// Kernel 2: sequential scan. grid = 2 (dir), block = 64 (ONE wave).
// ---------------------------------------------------------------------------
__global__ __launch_bounds__(64, 1) void scan_kernel(
    const float* __restrict__ WhhL,
    const float* __restrict__ WhhR,
    const float* __restrict__ gxp,
    float* __restrict__ hout)
{
    const int dir = blockIdx.x;
    const float* Whh = dir ? WhhR : WhhL;

    const int dd = threadIdx.x;           // lane == hidden unit
    const bool actv = (dd < D_DIM);

    // All 4 Whh rows of unit dd, as float2 pairs (rows are 240 B, 8B-aligned).
    v2f w2[4][30];
    #pragma unroll
    for (int g = 0; g < 4; ++g) {
        const float* row = Whh + (size_t)(g * 60 + (actv ? dd : 0)) * D_DIM;
        #pragma unroll
        for (int kk = 0; kk < 30; ++kk) {
            v2f v; v.x = 0.f; v.y = 0.f;
            if (actv) v = *(const v2f*)(row + 2 * kk);
            w2[g][kk] = v;
        }
    }

    __shared__ __align__(16) float hbuf[64];
    hbuf[dd] = 0.f;        // all 64 lanes; single wave -> no barrier needed

    float c = 0.f, hmine = 0.f;
    const float4* G = (const float4*)gxp + (size_t)dir * T_LEN * 64 + dd;

    // prefetch ring, depth 4 (one dwordx4 per step)
    float4 r0 = G[0];
    float4 r1 = G[64];
    float4 r2 = G[2 * 64];
    float4 r3 = G[3 * 64];

    for (int t = 0; t < T_LEN; ++t) {
        const float4 gx = r0;
        r0 = r1; r1 = r2; r2 = r3;
        r3 = (t + 4 < T_LEN) ? G[(size_t)(t + 4) * 64] : make_float4(0.f, 0.f, 0.f, 0.f);

        // gates_pre = gx + Whh[unit dd's 4 rows] . h   (float2 accumulators)
        v2f a0; a0.x = gx.x; a0.y = 0.f;
        v2f a1; a1.x = gx.y; a1.y = 0.f;
        v2f a2; a2.x = gx.z; a2.y = 0.f;
        v2f a3; a3.x = gx.w; a3.y = 0.f;

        const float4* h4 = (const float4*)hbuf;   // broadcast reads, 15 x b128
        #pragma unroll
        for (int i = 0; i < 15; ++i) {
            float4 hv = h4[i];
            v2f hlo; hlo.x = hv.x; hlo.y = hv.y;
            v2f hhi; hhi.x = hv.z; hhi.y = hv.w;
            a0 = __builtin_elementwise_fma(w2[0][2 * i], hlo, a0);
            a0 = __builtin_elementwise_fma(w2[0][2 * i + 1], hhi, a0);
            a1 = __builtin_elementwise_fma(w2[1][2 * i], hlo, a1);
            a1 = __builtin_elementwise_fma(w2[1][2 * i + 1], hhi, a1);
            a2 = __builtin_elementwise_fma(w2[2][2 * i], hlo, a2);
            a2 = __builtin_elementwise_fma(w2[2][2 * i + 1], hhi, a2);
            a3 = __builtin_elementwise_fma(w2[3][2 * i], hlo, a3);
            a3 = __builtin_elementwise_fma(w2[3][2 * i + 1], hhi, a3);
        }
        const float g0 = a0.x + a0.y;   // i
        const float g1 = a1.x + a1.y;   // f
        const float g2 = a2.x + a2.y;   // cg
        const float g3 = a3.x + a3.y;   // o

        const float i_ = fast_rcp(1.f + __expf(-g0));
        const float f_ = fast_rcp(1.f + __expf(-g1));
        const float cg = 1.f - 2.f * fast_rcp(__expf(2.f * g2) + 1.f);
        const float o_ = fast_rcp(1.f + __expf(-g3));

        c = f_ * c + i_ * cg;
        const float th = 1.f - 2.f * fast_rcp(__expf(2.f * c) + 1.f);
        hmine = o_ * th;

        // Same-wave LDS write; reads above already consumed hbuf, and the
        // compiler orders write->read via lgkmcnt (no barrier, single wave).
        hbuf[dd] = actv ? hmine : 0.f;
    }

    if (actv) hout[dir * 64 + dd] = hmine;
}

// ---------------------------------------------------------------------------
// Kernel 3: out[c] = Why_L[c,:] @ h_L + Why_R[c,:] @ h_R   (5 fp32 outputs)
// ---------------------------------------------------------------------------
__global__ __launch_bounds__(64) void out_kernel(
    const float* __restrict__ WhyL,
    const float* __restrict__ WhyR,
    const float* __restrict__ hout,
    float* __restrict__ out)
{
    const int cI = threadIdx.x;
    if (cI < 5) {
        float s = 0.f;
        #pragma unroll
        for (int d = 0; d < D_DIM; ++d) {
            s += WhyL[cI * D_DIM + d] * hout[d];
            s += WhyR[cI * D_DIM + d] * hout[64 + d];
        }
        out[cI] = s;
    }
}

extern "C" void kernel_launch(void* const* d_in, const int* in_sizes, int n_in,
                              void* d_out, int out_size, void* d_ws, size_t ws_size,
                              hipStream_t stream) {
    const int*   tokens = (const int*)d_in[0];
    const float* emb    = (const float*)d_in[1];
    const float* WxhL   = (const float*)d_in[2];
    const float* WhhL   = (const float*)d_in[3];
    const float* bxhL   = (const float*)d_in[4];
    const float* bhhL   = (const float*)d_in[5];
    const float* WxhR   = (const float*)d_in[6];
    const float* WhhR   = (const float*)d_in[7];
    const float* bxhR   = (const float*)d_in[8];
    const float* bhhR   = (const float*)d_in[9];
    const float* WhyL   = (const float*)d_in[10];
    const float* WhyR   = (const float*)d_in[11];

    float* gxp  = (float*)d_ws;                       // 2*8192*256 floats = 16 MB
    float* hout = gxp + (size_t)2 * T_LEN * 256;      // 128 floats

    dim3 g1(T_LEN / TB, 2);
    gates_kernel<<<g1, 256, 0, stream>>>(tokens, emb, WxhL, bxhL, bhhL,
                                         WxhR, bxhR, bhhR, gxp);
    scan_kernel<<<2, 64, 0, stream>>>(WhhL, WhhR, gxp, hout);
    out_kernel<<<1, 64, 0, stream>>>(WhyL, WhyR, hout, (float*)d_out);
}